// Round 3
// baseline (193.861 us; speedup 1.0000x reference)
//
#include <hip/hip_runtime.h>

// CTC batch loss (keras ctc_batch_cost), B=256, T=512, C=256, U=64.
// One 64-lane wave per batch, one block per CU. Lane l owns extended states
// 2l (blank) and 2l+1 (label l); lane 63 also owns state 128. Linear-domain
// forward recurrence with wave-uniform power-of-2 rescale every 8 steps.
//
// Data path (new this round): instead of per-lane scattered gathers
// (64 lanes over 16 cache lines per step), each time-row (256 floats = 1KB)
// is staged with ONE coalesced global_load_lds dwordx4 (64 lanes x 16B)
// into LDS, triple-buffered with prefetch depth 2 (48 loads in flight,
// counted vmcnt(32) waits -- never drained to 0 in the main loop). Labels
// are time-invariant, so each lane's LDS gather address is loop-constant:
// lab = row[label] (random banks, ~2-4-way conflicts), blk = row[255]
// (uniform address -> broadcast).

constexpr int B = 256, T = 512, C = 256, U = 64;
constexpr int CH = 16;      // time-steps per chunk
constexpr int NBUF = 3;     // LDS chunk buffers (48 KB total)
constexpr int NCHUNK = 32;  // ceil(511 / 16)
#define EPSF 1e-7f

__device__ __forceinline__ float dpp_wave_shr1(float x) {
    // alpha[2l-1]: previous lane's a_odd; lane 0 gets 0 (bound_ctrl).
    return __int_as_float(__builtin_amdgcn_update_dpp(
        0, __float_as_int(x), 0x138, 0xf, 0xf, true));
}

#define DPPMAX(ctrl)                                                      \
    {                                                                     \
        float x_ = __int_as_float(__builtin_amdgcn_update_dpp(            \
            0, __float_as_int(m_), (ctrl), 0xf, 0xf, true));              \
        m_ = fmaxf(m_, x_);                                               \
    }

#define RESCALE()                                                         \
    {                                                                     \
        float m_ = fmaxf(fmaxf(a_even, a_odd), a_top);                    \
        DPPMAX(0x111) DPPMAX(0x112) DPPMAX(0x114) DPPMAX(0x118)           \
        DPPMAX(0x142) DPPMAX(0x143)                                       \
        const float mx_ = __int_as_float(                                 \
            __builtin_amdgcn_readlane(__float_as_int(m_), 63));           \
        int e_ = (__float_as_int(mx_) >> 23) & 0xff;                      \
        int k_ = 187 - e_;                                                \
        k_ = k_ > 127 ? 127 : k_;                                         \
        const float s_ = __int_as_float((k_ + 127) << 23);                \
        a_even *= s_; a_odd *= s_; a_top *= s_;                           \
        esum += k_;                                                       \
    }

// Issue 16 coalesced row loads (1 KB each) for chunk cc into rows[cc % NBUF].
// Per-lane global source (row + lane*16B); wave-uniform LDS dest: HW writes
// lane l at dest + 16*l, which is exactly the linear row copy.
#define STAGE(cc)                                                          \
    {                                                                      \
        const int cs_ = (cc);                                              \
        float* lbase_ = &rows[cs_ % NBUF][0][0];                           \
        _Pragma("unroll")                                                  \
        for (int i = 0; i < CH; ++i) {                                     \
            int t = 1 + cs_ * CH + i;                                      \
            t = t < T ? t : T - 1;                                         \
            const float* g_ = rowp + (size_t)t * C + (lane << 2);          \
            __builtin_amdgcn_global_load_lds(                              \
                (const __attribute__((address_space(1))) void*)g_,         \
                (__attribute__((address_space(3))) void*)(lbase_ + i * C), \
                16, 0, 0);                                                 \
        }                                                                  \
    }

// Read chunk cc's per-step probabilities from LDS into registers.
#define LDS_READ(cc)                                                       \
    {                                                                      \
        const int cr_ = (cc);                                              \
        float(*row_)[C] = rows[cr_ % NBUF];                                \
        _Pragma("unroll")                                                  \
        for (int i = 0; i < CH; ++i) {                                     \
            lab[i] = row_[i][label];                                       \
            blk[i] = row_[i][C - 1];                                       \
        }                                                                  \
    }

// NSTEPS recurrence steps. t = 1 + cc*CH + i, so (t & 7) == 0 iff
// ((1 + i) & 7) == 0 (CH is a multiple of 8) -- compile-time cadence.
#define COMP_CHUNK(NSTEPS)                                                 \
    {                                                                      \
        _Pragma("unroll")                                                  \
        for (int i = 0; i < (NSTEPS); ++i) {                               \
            const float pb = blk[i] + EPSF;                                \
            const float pl = lab[i] + EPSF;                                \
            const float po = dpp_wave_shr1(a_odd);                         \
            const float skp = skip_ok ? po : 0.f;                          \
            const float ne = (a_even + po) * pb;                           \
            const float no = (a_odd + a_even + skp) * pl;                  \
            const float nt = (a_top + a_odd) * pb;                         \
            a_even = ne; a_odd = no; a_top = nt;                           \
            if (((1 + i) & 7) == 0) RESCALE();                             \
        }                                                                  \
    }

__global__ __launch_bounds__(64) void ctc_kernel(const int* __restrict__ y_true,
                                                 const float* __restrict__ y_pred,
                                                 float* __restrict__ out) {
    __shared__ float rows[NBUF][CH][C];  // 3 * 16 * 1KB = 48 KB
    const int b = blockIdx.x;
    const int lane = threadIdx.x;
    const int label = y_true[b * U + lane];
    const int label_prev = __shfl_up(label, 1);
    const bool skip_ok = (lane > 0) && (label != label_prev);
    const float* __restrict__ rowp = y_pred + (size_t)b * (T * C);

    // t = 0 init (linear domain; unreachable states = 0).
    float a_even, a_odd, a_top;
    {
        const float pb = rowp[C - 1] + EPSF;
        const float pl = rowp[label] + EPSF;
        a_even = (lane == 0) ? pb : 0.f;
        a_odd  = (lane == 0) ? pl : 0.f;
        a_top  = 0.f;
    }
    int esum = 0;  // stored = true * 2^esum

    // Prologue: fill the pipeline with chunks 0, 1, 2 (48 loads in flight).
    STAGE(0);
    STAGE(1);
    STAGE(2);

    float lab[CH], blk[CH];

    // Main loop: chunks 0..29. Steady-state outstanding before the wait:
    // chunks c, c+1, c+2 = 48 loads; vmcnt(32) guarantees chunk c landed.
    for (int c = 0; c < 30; ++c) {
        asm volatile("s_waitcnt vmcnt(32)" ::: "memory");
        __builtin_amdgcn_sched_barrier(0);
        LDS_READ(c);
        // Drain the LDS reads before re-targeting this buffer (chunk c+3
        // writes rows[c % NBUF]); also covers the data dependency below.
        asm volatile("s_waitcnt lgkmcnt(0)" ::: "memory");
        __builtin_amdgcn_sched_barrier(0);
        if (c <= 28) STAGE(c + 3);
        COMP_CHUNK(CH);
    }

    // Epilogue chunk 30: outstanding = chunks 30, 31 (32 loads).
    {
        asm volatile("s_waitcnt vmcnt(16)" ::: "memory");
        __builtin_amdgcn_sched_barrier(0);
        LDS_READ(30);
        COMP_CHUNK(CH);
    }
    // Epilogue chunk 31: t = 497..511 -> 15 steps.
    {
        asm volatile("s_waitcnt vmcnt(0)" ::: "memory");
        __builtin_amdgcn_sched_barrier(0);
        LDS_READ(31);
        COMP_CHUNK(CH - 1);
    }

    // loss = -ln(alpha[128] + alpha[127]); true = stored * 2^-esum
    if (lane == 63)
        out[b] = -logf(a_top + a_odd) + (float)esum * 0.69314718055994531f;
}

extern "C" void kernel_launch(void* const* d_in, const int* in_sizes, int n_in,
                              void* d_out, int out_size, void* d_ws, size_t ws_size,
                              hipStream_t stream) {
    const int* y_true   = (const int*)d_in[0];
    const float* y_pred = (const float*)d_in[1];
    float* out = (float*)d_out;
    hipLaunchKernelGGL(ctc_kernel, dim3(B), dim3(64), 0, stream,
                       y_true, y_pred, out);
}